// Round 3
// baseline (916.031 us; speedup 1.0000x reference)
//
#include <hip/hip_runtime.h>
#include <hip/hip_fp16.h>

#define N_NODES 20000
#define N_EDGES 320000
#define MSG_ROW 576
#define MSG_OFF 11520000   // N_NODES * 576 : sc region of d_out (fallback path msg buffer)
#define SCAN_BS 256
#define NBLK_SCAN ((N_NODES + SCAN_BS - 1) / SCAN_BS)   // 79

__device__ __forceinline__ float silu_f(float x) {
    return x * (1.0f / (1.0f + __expf(-x)));
}

// accumulate a2[i][j] = sum_u src[u*64+e0+j] * W[u*64+c0+i]   (src in LDS, W global)
__device__ __forceinline__ void layer_accum(const float* src, const float* __restrict__ W,
                                            float a2[4][4], int c0, int e0) {
#pragma unroll
    for (int i = 0; i < 4; ++i)
#pragma unroll
        for (int j = 0; j < 4; ++j) a2[i][j] = 0.f;
#pragma unroll 8
    for (int u = 0; u < 64; ++u) {
        const float4 h4 = *(const float4*)&src[(u << 6) + e0];
        const float4 w4 = *(const float4*)&W[(u << 6) + c0];
        const float hv[4] = {h4.x, h4.y, h4.z, h4.w};
        const float wv[4] = {w4.x, w4.y, w4.z, w4.w};
#pragma unroll
        for (int i = 0; i < 4; ++i)
#pragma unroll
            for (int j = 0; j < 4; ++j) a2[i][j] += wv[i] * hv[j];
    }
}

__device__ __forceinline__ void layer_store(float* dst, const float a2[4][4],
                                            float scale, int c0, int e0) {
#pragma unroll
    for (int i = 0; i < 4; ++i) {
        float4 v;
        v.x = silu_f(a2[i][0] * scale);
        v.y = silu_f(a2[i][1] * scale);
        v.z = silu_f(a2[i][2] * scale);
        v.w = silu_f(a2[i][3] * scale);
        *(float4*)&dst[((c0 + i) << 6) + e0] = v;
    }
}

// ============================ CSR build ============================

__global__ __launch_bounds__(256)
void hist_kernel(const int* __restrict__ eidx, int* __restrict__ counts) {
    const int e = blockIdx.x * 256 + threadIdx.x;
    if (e < N_EDGES) atomicAdd(&counts[eidx[N_EDGES + e]], 1);
}

__global__ __launch_bounds__(SCAN_BS)
void scan1_kernel(const int* __restrict__ counts, int* __restrict__ offs,
                  int* __restrict__ bsum) {
    __shared__ int sm[SCAN_BS];
    const int tid = threadIdx.x;
    const int i = blockIdx.x * SCAN_BS + tid;
    const int v = (i < N_NODES) ? counts[i] : 0;
    sm[tid] = v;
    __syncthreads();
#pragma unroll
    for (int off = 1; off < SCAN_BS; off <<= 1) {
        const int t = (tid >= off) ? sm[tid - off] : 0;
        __syncthreads();
        sm[tid] += t;
        __syncthreads();
    }
    if (i < N_NODES) offs[i] = sm[tid] - v;          // block-local exclusive
    if (tid == SCAN_BS - 1) bsum[blockIdx.x] = sm[tid];
}

__global__ __launch_bounds__(128)
void scan2_kernel(const int* __restrict__ bsum, int* __restrict__ bbase,
                  int* __restrict__ offs) {
    __shared__ int sm[128];
    const int tid = threadIdx.x;
    const int v = (tid < NBLK_SCAN) ? bsum[tid] : 0;
    sm[tid] = v;
    __syncthreads();
#pragma unroll
    for (int off = 1; off < 128; off <<= 1) {
        const int t = (tid >= off) ? sm[tid - off] : 0;
        __syncthreads();
        sm[tid] += t;
        __syncthreads();
    }
    if (tid < NBLK_SCAN) bbase[tid] = sm[tid] - v;   // exclusive base per block
    if (tid == 127) offs[N_NODES] = sm[127];
}

__global__ __launch_bounds__(SCAN_BS)
void scan3_kernel(int* __restrict__ offs, const int* __restrict__ bbase,
                  int* __restrict__ cursor) {
    const int i = blockIdx.x * SCAN_BS + threadIdx.x;
    if (i < N_NODES) {
        const int o = offs[i] + bbase[blockIdx.x];
        offs[i] = o;
        cursor[i] = o;
    }
}

__global__ __launch_bounds__(256)
void scatter_kernel(const int* __restrict__ eidx, int* __restrict__ cursor,
                    int* __restrict__ order) {
    const int e = blockIdx.x * 256 + threadIdx.x;
    if (e < N_EDGES) {
        const int pos = atomicAdd(&cursor[eidx[N_EDGES + e]], 1);
        order[pos] = e;
    }
}

// ============================ edge MLP -> wx (fp16) ============================

__global__ __launch_bounds__(256, 8)
void edge_mlp_kernel(const float* __restrict__ length,   // E x 8
                     const float* __restrict__ nf,       // N x 64
                     const float* __restrict__ W1,
                     const float* __restrict__ W2,
                     const float* __restrict__ W3,
                     const float* __restrict__ W4,
                     const int*   __restrict__ eidx,
                     __half* __restrict__ wx)            // E x 192 fp16
{
    __shared__ float buf[4096];   // single in-place activation buffer [u][e]
    __shared__ float lenS[512];   // [k][e]
    __shared__ int   sendS[64];

    const int tid = threadIdx.x;
    const int tx = tid & 15;
    const int ty = tid >> 4;
    const int c0 = tx << 2;
    const int e0 = ty << 2;
    const int ebase = blockIdx.x << 6;

    for (int i = tid; i < 512; i += 256) {
        const int e = i >> 3, k = i & 7;
        lenS[(k << 6) + e] = length[((ebase + e) << 3) + k];
    }
    if (tid < 64) sendS[tid] = eidx[ebase + tid];
    __syncthreads();

    // ---- layer 1: 8 -> 64 ----
    {
        float a2[4][4];
#pragma unroll
        for (int i = 0; i < 4; ++i)
#pragma unroll
            for (int j = 0; j < 4; ++j) a2[i][j] = 0.f;
#pragma unroll
        for (int k = 0; k < 8; ++k) {
            const float4 h4 = *(const float4*)&lenS[(k << 6) + e0];
            const float4 w4 = *(const float4*)&W1[(k << 6) + c0];
            const float hv[4] = {h4.x, h4.y, h4.z, h4.w};
            const float wv[4] = {w4.x, w4.y, w4.z, w4.w};
#pragma unroll
            for (int i = 0; i < 4; ++i)
#pragma unroll
                for (int j = 0; j < 4; ++j) a2[i][j] += wv[i] * hv[j];
        }
        layer_store(buf, a2, 0.35355339059327373f, c0, e0);
    }
    __syncthreads();

    // ---- layer 2 (in-place: regs -> sync -> write-back) ----
    {
        float a2[4][4];
        layer_accum(buf, W2, a2, c0, e0);
        __syncthreads();
        layer_store(buf, a2, 0.125f, c0, e0);
    }
    __syncthreads();

    // ---- layer 3 ----
    {
        float a2[4][4];
        layer_accum(buf, W3, a2, c0, e0);
        __syncthreads();
        layer_store(buf, a2, 0.125f, c0, e0);
    }
    __syncthreads();

    // ---- layer 4: 64 -> 192 (no silu) ----
    float wacc[3][4][4];
#pragma unroll
    for (int l = 0; l < 3; ++l)
#pragma unroll
        for (int i = 0; i < 4; ++i)
#pragma unroll
            for (int j = 0; j < 4; ++j) wacc[l][i][j] = 0.f;

#pragma unroll 4
    for (int u = 0; u < 64; ++u) {
        const float4 h4 = *(const float4*)&buf[(u << 6) + e0];
        const float hv[4] = {h4.x, h4.y, h4.z, h4.w};
#pragma unroll
        for (int l = 0; l < 3; ++l) {
            const float4 w4 = *(const float4*)&W4[u * 192 + (l << 6) + c0];
            const float wv[4] = {w4.x, w4.y, w4.z, w4.w};
#pragma unroll
            for (int i = 0; i < 4; ++i)
#pragma unroll
                for (int j = 0; j < 4; ++j) wacc[l][i][j] += wv[i] * hv[j];
        }
    }

    // wx[e][l*64+c] = 0.125 * w * nf[sender][c]  (fp16, coalesced 8B stores)
#pragma unroll
    for (int j = 0; j < 4; ++j) {
        const int e = e0 + j;
        const int snd = sendS[e];
        const float4 nf4 = *(const float4*)&nf[(snd << 6) + c0];
        __half* wrow = wx + (size_t)(ebase + e) * 192;
#pragma unroll
        for (int l = 0; l < 3; ++l) {
            const float v0 = wacc[l][0][j] * 0.125f * nf4.x;
            const float v1 = wacc[l][1][j] * 0.125f * nf4.y;
            const float v2 = wacc[l][2][j] * 0.125f * nf4.z;
            const float v3 = wacc[l][3][j] * 0.125f * nf4.w;
            __half2 p0 = __floats2half2_rn(v0, v1);
            __half2 p1 = __floats2half2_rn(v2, v3);
            *(__half2*)&wrow[(l << 6) + c0]     = p0;
            *(__half2*)&wrow[(l << 6) + c0 + 2] = p1;
        }
    }
}

// ============================ fused gather + node transform ============================

__global__ __launch_bounds__(256, 8)
void gather_node_kernel(const __half* __restrict__ wx,     // E x 192 fp16
                        const float* __restrict__ ea,      // E x 9
                        const int* __restrict__ offs,      // N+1
                        const int* __restrict__ order,     // E
                        const float* __restrict__ nf,      // N x 64
                        const float* __restrict__ na,      // N x 4
                        const float* __restrict__ Wl,      // 3 x 64 x 64
                        const float* __restrict__ Wsc,     // 4 x 64 x 64
                        float* __restrict__ out)
{
    __shared__ float ms[4][576];
    __shared__ float fs[4][64];
    const int tid = threadIdx.x;
    const int wid = tid >> 6;
    const int v   = tid & 63;
    const int n   = (blockIdx.x << 2) + wid;
    const int beg = offs[n];
    const int end = offs[n + 1];

    float a0 = 0.f, a1[3] = {0.f, 0.f, 0.f}, a2[5] = {0.f, 0.f, 0.f, 0.f, 0.f};
    for (int k = beg; k < end; ++k) {
        int e = order[k];
        e = __builtin_amdgcn_readfirstlane(e);   // wave-uniform -> scalar loads for y
        const __half* wr = wx + (size_t)e * 192;
        const float x0 = __half2float(wr[v]);
        const float x1 = __half2float(wr[64 + v]);
        const float x2 = __half2float(wr[128 + v]);
        const float* y = ea + e * 9;
        a0 += x0 * y[0];
#pragma unroll
        for (int m = 0; m < 3; ++m) a1[m] += x1 * y[1 + m];
#pragma unroll
        for (int m = 0; m < 5; ++m) a2[m] += x2 * y[4 + m];
    }

    // transpose msg row through this wave's LDS slice (wave-internal, no block barrier)
    float* m = ms[wid];
    m[v] = a0;
#pragma unroll
    for (int mm = 0; mm < 3; ++mm) m[64 + v * 3 + mm] = a1[mm];
#pragma unroll
    for (int mm = 0; mm < 5; ++mm) m[256 + v * 5 + mm] = a2[mm];
    fs[wid][v] = nf[(n << 6) + v];
    // same-wave lockstep: drain LDS writes before cross-lane reads
    asm volatile("s_waitcnt lgkmcnt(0)" ::: "memory");

    float o9[9];
#pragma unroll
    for (int j = 0; j < 9; ++j) o9[j] = 0.f;
    const float* m1 = m + 64;
    const float* m2 = m + 256;

#pragma unroll 8
    for (int u = 0; u < 64; ++u) {
        const float w0 = Wl[(u << 6) + v];
        const float w1 = Wl[4096 + (u << 6) + v];
        const float w2 = Wl[8192 + (u << 6) + v];
        o9[0] += m[u] * w0;
        o9[1] += m1[u * 3 + 0] * w1;
        o9[2] += m1[u * 3 + 1] * w1;
        o9[3] += m1[u * 3 + 2] * w1;
        o9[4] += m2[u * 5 + 0] * w2;
        o9[5] += m2[u * 5 + 1] * w2;
        o9[6] += m2[u * 5 + 2] * w2;
        o9[7] += m2[u * 5 + 3] * w2;
        o9[8] += m2[u * 5 + 4] * w2;
    }
#pragma unroll
    for (int j = 0; j < 9; ++j) out[n * MSG_ROW + v * 9 + j] = o9[j] * 0.125f;

    // sc0[n][v] = (1/16) * sum_a attr[a] * sum_u feat[u] * Wsc[a][u][v]
    const float b0 = na[(n << 2) + 0];
    const float b1 = na[(n << 2) + 1];
    const float b2 = na[(n << 2) + 2];
    const float b3 = na[(n << 2) + 3];
    float sacc = 0.f;
#pragma unroll 8
    for (int u = 0; u < 64; ++u) {
        const float f = fs[wid][u];
        sacc += f * (b0 * Wsc[(u << 6) + v] + b1 * Wsc[4096 + (u << 6) + v] +
                     b2 * Wsc[8192 + (u << 6) + v] + b3 * Wsc[12288 + (u << 6) + v]);
    }
    float* scrow = out + MSG_OFF + n * MSG_ROW;
    scrow[v] = sacc * 0.0625f;
#pragma unroll
    for (int j = 1; j < 9; ++j) scrow[(j << 6) + v] = 0.f;
}

// ============================ fallback (atomic) path ============================

__global__ __launch_bounds__(256, 4)
void edge_kernel_atomic(const float* __restrict__ length,
                        const float* __restrict__ nf,
                        const float* __restrict__ ea,
                        const float* __restrict__ W1,
                        const float* __restrict__ W2,
                        const float* __restrict__ W3,
                        const float* __restrict__ W4,
                        const int*   __restrict__ eidx,
                        float* __restrict__ msg)
{
    __shared__ float buf[4096];
    __shared__ float lenS[512];
    __shared__ float Ys[576];
    __shared__ int   sendS[64];
    __shared__ int   recvS[64];

    const int tid = threadIdx.x;
    const int tx = tid & 15;
    const int ty = tid >> 4;
    const int c0 = tx << 2;
    const int e0 = ty << 2;
    const int ebase = blockIdx.x << 6;

    for (int i = tid; i < 512; i += 256) {
        const int e = i >> 3, k = i & 7;
        lenS[(k << 6) + e] = length[((ebase + e) << 3) + k];
    }
    for (int i = tid; i < 576; i += 256) Ys[i] = ea[ebase * 9 + i];
    if (tid < 64) {
        sendS[tid] = eidx[ebase + tid];
        recvS[tid] = eidx[N_EDGES + ebase + tid];
    }
    __syncthreads();

    {
        float a2[4][4];
#pragma unroll
        for (int i = 0; i < 4; ++i)
#pragma unroll
            for (int j = 0; j < 4; ++j) a2[i][j] = 0.f;
#pragma unroll
        for (int k = 0; k < 8; ++k) {
            const float4 h4 = *(const float4*)&lenS[(k << 6) + e0];
            const float4 w4 = *(const float4*)&W1[(k << 6) + c0];
            const float hv[4] = {h4.x, h4.y, h4.z, h4.w};
            const float wv[4] = {w4.x, w4.y, w4.z, w4.w};
#pragma unroll
            for (int i = 0; i < 4; ++i)
#pragma unroll
                for (int j = 0; j < 4; ++j) a2[i][j] += wv[i] * hv[j];
        }
        layer_store(buf, a2, 0.35355339059327373f, c0, e0);
    }
    __syncthreads();
    {
        float a2[4][4];
        layer_accum(buf, W2, a2, c0, e0);
        __syncthreads();
        layer_store(buf, a2, 0.125f, c0, e0);
    }
    __syncthreads();
    {
        float a2[4][4];
        layer_accum(buf, W3, a2, c0, e0);
        __syncthreads();
        layer_store(buf, a2, 0.125f, c0, e0);
    }
    __syncthreads();

    float wacc[3][4][4];
#pragma unroll
    for (int l = 0; l < 3; ++l)
#pragma unroll
        for (int i = 0; i < 4; ++i)
#pragma unroll
            for (int j = 0; j < 4; ++j) wacc[l][i][j] = 0.f;
#pragma unroll 4
    for (int u = 0; u < 64; ++u) {
        const float4 h4 = *(const float4*)&buf[(u << 6) + e0];
        const float hv[4] = {h4.x, h4.y, h4.z, h4.w};
#pragma unroll
        for (int l = 0; l < 3; ++l) {
            const float4 w4 = *(const float4*)&W4[u * 192 + (l << 6) + c0];
            const float wv[4] = {w4.x, w4.y, w4.z, w4.w};
#pragma unroll
            for (int i = 0; i < 4; ++i)
#pragma unroll
                for (int j = 0; j < 4; ++j) wacc[l][i][j] += wv[i] * hv[j];
        }
    }

#pragma unroll
    for (int j = 0; j < 4; ++j) {
        const int e = e0 + j;
        const int snd = sendS[e];
        const int rcv = recvS[e];
        const float4 nf4 = *(const float4*)&nf[(snd << 6) + c0];
        const float nfv[4] = {nf4.x, nf4.y, nf4.z, nf4.w};
        float* mrow = msg + rcv * MSG_ROW;
        const float y0 = Ys[e * 9 + 0];
        float y1[3], y2[5];
#pragma unroll
        for (int m = 0; m < 3; ++m) y1[m] = Ys[e * 9 + 1 + m];
#pragma unroll
        for (int m = 0; m < 5; ++m) y2[m] = Ys[e * 9 + 4 + m];
#pragma unroll
        for (int i = 0; i < 4; ++i) {
            const int c = c0 + i;
            const float wx0 = wacc[0][i][j] * 0.125f * nfv[i];
            const float wx1 = wacc[1][i][j] * 0.125f * nfv[i];
            const float wx2 = wacc[2][i][j] * 0.125f * nfv[i];
            atomicAdd(&mrow[c], wx0 * y0);
#pragma unroll
            for (int m = 0; m < 3; ++m) atomicAdd(&mrow[64 + c * 3 + m], wx1 * y1[m]);
#pragma unroll
            for (int m = 0; m < 5; ++m) atomicAdd(&mrow[256 + c * 5 + m], wx2 * y2[m]);
        }
    }
}

__global__ __launch_bounds__(256, 4)
void node_kernel(const float* __restrict__ nf,
                 const float* __restrict__ na,
                 const float* __restrict__ Wl,
                 const float* __restrict__ Wsc,
                 float* __restrict__ out)
{
    __shared__ float ms[4][576];
    __shared__ float fs[4][64];
    const int tid = threadIdx.x;
    const int wid = tid >> 6;
    const int v   = tid & 63;
    const int n   = (blockIdx.x << 2) + wid;
    const float* msg = out + MSG_OFF;

#pragma unroll
    for (int j = 0; j < 9; ++j)
        ms[wid][(j << 6) + v] = msg[n * MSG_ROW + (j << 6) + v];
    fs[wid][v] = nf[(n << 6) + v];
    __syncthreads();

    float o9[9];
#pragma unroll
    for (int j = 0; j < 9; ++j) o9[j] = 0.f;
    const float* m0 = &ms[wid][0];
    const float* m1 = &ms[wid][64];
    const float* m2 = &ms[wid][256];

#pragma unroll 8
    for (int u = 0; u < 64; ++u) {
        const float w0 = Wl[(u << 6) + v];
        const float w1 = Wl[4096 + (u << 6) + v];
        const float w2 = Wl[8192 + (u << 6) + v];
        o9[0] += m0[u] * w0;
        o9[1] += m1[u * 3 + 0] * w1;
        o9[2] += m1[u * 3 + 1] * w1;
        o9[3] += m1[u * 3 + 2] * w1;
        o9[4] += m2[u * 5 + 0] * w2;
        o9[5] += m2[u * 5 + 1] * w2;
        o9[6] += m2[u * 5 + 2] * w2;
        o9[7] += m2[u * 5 + 3] * w2;
        o9[8] += m2[u * 5 + 4] * w2;
    }
#pragma unroll
    for (int j = 0; j < 9; ++j) out[n * MSG_ROW + v * 9 + j] = o9[j] * 0.125f;

    const float b0 = na[(n << 2) + 0];
    const float b1 = na[(n << 2) + 1];
    const float b2 = na[(n << 2) + 2];
    const float b3 = na[(n << 2) + 3];
    float sacc = 0.f;
#pragma unroll 8
    for (int u = 0; u < 64; ++u) {
        const float f = fs[wid][u];
        sacc += f * (b0 * Wsc[(u << 6) + v] + b1 * Wsc[4096 + (u << 6) + v] +
                     b2 * Wsc[8192 + (u << 6) + v] + b3 * Wsc[12288 + (u << 6) + v]);
    }
    float* scrow = out + MSG_OFF + n * MSG_ROW;
    scrow[v] = sacc * 0.0625f;
#pragma unroll
    for (int j = 1; j < 9; ++j) scrow[(j << 6) + v] = 0.f;
}

extern "C" void kernel_launch(void* const* d_in, const int* in_sizes, int n_in,
                              void* d_out, int out_size, void* d_ws, size_t ws_size,
                              hipStream_t stream) {
    const float* length = (const float*)d_in[0];
    const float* nfeat  = (const float*)d_in[1];
    const float* nattr  = (const float*)d_in[2];
    const float* eattr  = (const float*)d_in[3];
    const float* W1     = (const float*)d_in[4];
    const float* W2     = (const float*)d_in[5];
    const float* W3     = (const float*)d_in[6];
    const float* W4     = (const float*)d_in[7];
    const float* Wl     = (const float*)d_in[8];
    const float* Wsc    = (const float*)d_in[9];
    const int*   eidx   = (const int*)d_in[10];
    float* out = (float*)d_out;

    // ws layout: wx[E*192 fp16] | counts[N] | offsets[N+1] | cursor[N] | order[E] | bsum[128] | bbase[128]
    __half* wx     = (__half*)d_ws;
    int*   counts  = (int*)((char*)d_ws + (size_t)N_EDGES * 192 * 2);
    int*   offsets = counts + N_NODES;
    int*   cursor  = offsets + N_NODES + 1;
    int*   order   = cursor + N_NODES;
    int*   bsum    = order + N_EDGES;
    int*   bbase   = bsum + 128;
    const size_t need = (size_t)N_EDGES * 192 * 2 +
                        (size_t)(N_NODES * 3 + 1 + N_EDGES + 256) * 4;

    if (ws_size >= need) {
        hipMemsetAsync(counts, 0, N_NODES * sizeof(int), stream);
        hist_kernel<<<N_EDGES / 256, 256, 0, stream>>>(eidx, counts);
        scan1_kernel<<<NBLK_SCAN, SCAN_BS, 0, stream>>>(counts, offsets, bsum);
        scan2_kernel<<<1, 128, 0, stream>>>(bsum, bbase, offsets);
        scan3_kernel<<<NBLK_SCAN, SCAN_BS, 0, stream>>>(offsets, bbase, cursor);
        scatter_kernel<<<N_EDGES / 256, 256, 0, stream>>>(eidx, cursor, order);
        edge_mlp_kernel<<<N_EDGES / 64, 256, 0, stream>>>(length, nfeat, W1, W2, W3, W4,
                                                          eidx, wx);
        gather_node_kernel<<<N_NODES / 4, 256, 0, stream>>>(wx, eattr, offsets, order,
                                                            nfeat, nattr, Wl, Wsc, out);
    } else {
        // fallback: atomic scatter path
        hipMemsetAsync(out + MSG_OFF, 0, (size_t)N_NODES * MSG_ROW * sizeof(float), stream);
        edge_kernel_atomic<<<N_EDGES / 64, 256, 0, stream>>>(length, nfeat, eattr,
                                                             W1, W2, W3, W4, eidx,
                                                             out + MSG_OFF);
        node_kernel<<<N_NODES / 4, 256, 0, stream>>>(nfeat, nattr, Wl, Wsc, out);
    }
}

// Round 4
// 392.911 us; speedup vs baseline: 2.3314x; 2.3314x over previous
//
#include <hip/hip_runtime.h>
#include <hip/hip_fp16.h>

#define N_NODES 20000
#define N_EDGES 320000
#define MSG_ROW 576
#define MSG_OFF 11520000   // N_NODES * 576 : sc region of d_out (fallback path msg buffer)
#define SCAN_BS 256
#define NBLK_SCAN ((N_NODES + SCAN_BS - 1) / SCAN_BS)   // 79

__device__ __forceinline__ float silu_f(float x) {
    return x * (1.0f / (1.0f + __expf(-x)));
}

// accumulate a2[i][j] = sum_u src[u*64+e0+j] * W[u*64+c0+i]   (src in LDS, W global)
__device__ __forceinline__ void layer_accum(const float* src, const float* __restrict__ W,
                                            float a2[4][4], int c0, int e0) {
#pragma unroll
    for (int i = 0; i < 4; ++i)
#pragma unroll
        for (int j = 0; j < 4; ++j) a2[i][j] = 0.f;
#pragma unroll 8
    for (int u = 0; u < 64; ++u) {
        const float4 h4 = *(const float4*)&src[(u << 6) + e0];
        const float4 w4 = *(const float4*)&W[(u << 6) + c0];
        const float hv[4] = {h4.x, h4.y, h4.z, h4.w};
        const float wv[4] = {w4.x, w4.y, w4.z, w4.w};
#pragma unroll
        for (int i = 0; i < 4; ++i)
#pragma unroll
            for (int j = 0; j < 4; ++j) a2[i][j] += wv[i] * hv[j];
    }
}

__device__ __forceinline__ void layer_store(float* dst, const float a2[4][4],
                                            float scale, int c0, int e0) {
#pragma unroll
    for (int i = 0; i < 4; ++i) {
        float4 v;
        v.x = silu_f(a2[i][0] * scale);
        v.y = silu_f(a2[i][1] * scale);
        v.z = silu_f(a2[i][2] * scale);
        v.w = silu_f(a2[i][3] * scale);
        *(float4*)&dst[((c0 + i) << 6) + e0] = v;
    }
}

// ============================ CSR build ============================

__global__ __launch_bounds__(256)
void hist_kernel(const int* __restrict__ eidx, int* __restrict__ counts) {
    const int e = blockIdx.x * 256 + threadIdx.x;
    if (e < N_EDGES) atomicAdd(&counts[eidx[N_EDGES + e]], 1);
}

__global__ __launch_bounds__(SCAN_BS)
void scan1_kernel(const int* __restrict__ counts, int* __restrict__ offs,
                  int* __restrict__ bsum) {
    __shared__ int sm[SCAN_BS];
    const int tid = threadIdx.x;
    const int i = blockIdx.x * SCAN_BS + tid;
    const int v = (i < N_NODES) ? counts[i] : 0;
    sm[tid] = v;
    __syncthreads();
#pragma unroll
    for (int off = 1; off < SCAN_BS; off <<= 1) {
        const int t = (tid >= off) ? sm[tid - off] : 0;
        __syncthreads();
        sm[tid] += t;
        __syncthreads();
    }
    if (i < N_NODES) offs[i] = sm[tid] - v;          // block-local exclusive
    if (tid == SCAN_BS - 1) bsum[blockIdx.x] = sm[tid];
}

__global__ __launch_bounds__(128)
void scan2_kernel(const int* __restrict__ bsum, int* __restrict__ bbase,
                  int* __restrict__ offs) {
    __shared__ int sm[128];
    const int tid = threadIdx.x;
    const int v = (tid < NBLK_SCAN) ? bsum[tid] : 0;
    sm[tid] = v;
    __syncthreads();
#pragma unroll
    for (int off = 1; off < 128; off <<= 1) {
        const int t = (tid >= off) ? sm[tid - off] : 0;
        __syncthreads();
        sm[tid] += t;
        __syncthreads();
    }
    if (tid < NBLK_SCAN) bbase[tid] = sm[tid] - v;   // exclusive base per block
    if (tid == 127) offs[N_NODES] = sm[127];
}

__global__ __launch_bounds__(SCAN_BS)
void scan3_kernel(int* __restrict__ offs, const int* __restrict__ bbase,
                  int* __restrict__ cursor) {
    const int i = blockIdx.x * SCAN_BS + threadIdx.x;
    if (i < N_NODES) {
        const int o = offs[i] + bbase[blockIdx.x];
        offs[i] = o;
        cursor[i] = o;
    }
}

__global__ __launch_bounds__(256)
void scatter_kernel(const int* __restrict__ eidx, int* __restrict__ cursor,
                    int* __restrict__ order) {
    const int e = blockIdx.x * 256 + threadIdx.x;
    if (e < N_EDGES) {
        const int pos = atomicAdd(&cursor[eidx[N_EDGES + e]], 1);
        order[pos] = e;
    }
}

// ============================ edge MLP -> wx (fp16) ============================
// __launch_bounds__(256,4): round-2-proven register shape (VGPR=64, no spill).
// (256,8) forced a 64-VGPR hard cap -> allocator spilled wacc[3][4][4] to
// scratch: FETCH +68MB, VALUBusy 56->16%, 3.3x slower. Do not raise again.

__global__ __launch_bounds__(256, 4)
void edge_mlp_kernel(const float* __restrict__ length,   // E x 8
                     const float* __restrict__ nf,       // N x 64
                     const float* __restrict__ W1,
                     const float* __restrict__ W2,
                     const float* __restrict__ W3,
                     const float* __restrict__ W4,
                     const int*   __restrict__ eidx,
                     __half* __restrict__ wx)            // E x 192 fp16
{
    __shared__ float buf[4096];   // single in-place activation buffer [u][e]
    __shared__ float lenS[512];   // [k][e]
    __shared__ int   sendS[64];

    const int tid = threadIdx.x;
    const int tx = tid & 15;
    const int ty = tid >> 4;
    const int c0 = tx << 2;
    const int e0 = ty << 2;
    const int ebase = blockIdx.x << 6;

    for (int i = tid; i < 512; i += 256) {
        const int e = i >> 3, k = i & 7;
        lenS[(k << 6) + e] = length[((ebase + e) << 3) + k];
    }
    if (tid < 64) sendS[tid] = eidx[ebase + tid];
    __syncthreads();

    // ---- layer 1: 8 -> 64 ----
    {
        float a2[4][4];
#pragma unroll
        for (int i = 0; i < 4; ++i)
#pragma unroll
            for (int j = 0; j < 4; ++j) a2[i][j] = 0.f;
#pragma unroll
        for (int k = 0; k < 8; ++k) {
            const float4 h4 = *(const float4*)&lenS[(k << 6) + e0];
            const float4 w4 = *(const float4*)&W1[(k << 6) + c0];
            const float hv[4] = {h4.x, h4.y, h4.z, h4.w};
            const float wv[4] = {w4.x, w4.y, w4.z, w4.w};
#pragma unroll
            for (int i = 0; i < 4; ++i)
#pragma unroll
                for (int j = 0; j < 4; ++j) a2[i][j] += wv[i] * hv[j];
        }
        layer_store(buf, a2, 0.35355339059327373f, c0, e0);
    }
    __syncthreads();

    // ---- layer 2 (in-place: regs -> sync -> write-back) ----
    {
        float a2[4][4];
        layer_accum(buf, W2, a2, c0, e0);
        __syncthreads();
        layer_store(buf, a2, 0.125f, c0, e0);
    }
    __syncthreads();

    // ---- layer 3 ----
    {
        float a2[4][4];
        layer_accum(buf, W3, a2, c0, e0);
        __syncthreads();
        layer_store(buf, a2, 0.125f, c0, e0);
    }
    __syncthreads();

    // ---- layer 4: 64 -> 192 (no silu), single-pass accumulate ----
    float wacc[3][4][4];
#pragma unroll
    for (int l = 0; l < 3; ++l)
#pragma unroll
        for (int i = 0; i < 4; ++i)
#pragma unroll
            for (int j = 0; j < 4; ++j) wacc[l][i][j] = 0.f;

#pragma unroll 4
    for (int u = 0; u < 64; ++u) {
        const float4 h4 = *(const float4*)&buf[(u << 6) + e0];
        const float hv[4] = {h4.x, h4.y, h4.z, h4.w};
#pragma unroll
        for (int l = 0; l < 3; ++l) {
            const float4 w4 = *(const float4*)&W4[u * 192 + (l << 6) + c0];
            const float wv[4] = {w4.x, w4.y, w4.z, w4.w};
#pragma unroll
            for (int i = 0; i < 4; ++i)
#pragma unroll
                for (int j = 0; j < 4; ++j) wacc[l][i][j] += wv[i] * hv[j];
        }
    }

    // wx[e][l*64+c] = 0.125 * w * nf[sender][c]  (fp16, coalesced 8B stores)
#pragma unroll
    for (int j = 0; j < 4; ++j) {
        const int e = e0 + j;
        const int snd = sendS[e];
        const float4 nf4 = *(const float4*)&nf[(snd << 6) + c0];
        __half* wrow = wx + (size_t)(ebase + e) * 192;
#pragma unroll
        for (int l = 0; l < 3; ++l) {
            const float v0 = wacc[l][0][j] * 0.125f * nf4.x;
            const float v1 = wacc[l][1][j] * 0.125f * nf4.y;
            const float v2 = wacc[l][2][j] * 0.125f * nf4.z;
            const float v3 = wacc[l][3][j] * 0.125f * nf4.w;
            __half2 p0 = __floats2half2_rn(v0, v1);
            __half2 p1 = __floats2half2_rn(v2, v3);
            *(__half2*)&wrow[(l << 6) + c0]     = p0;
            *(__half2*)&wrow[(l << 6) + c0 + 2] = p1;
        }
    }
}

// ============================ fused gather + node transform ============================

__global__ __launch_bounds__(256, 8)
void gather_node_kernel(const __half* __restrict__ wx,     // E x 192 fp16
                        const float* __restrict__ ea,      // E x 9
                        const int* __restrict__ offs,      // N+1
                        const int* __restrict__ order,     // E
                        const float* __restrict__ nf,      // N x 64
                        const float* __restrict__ na,      // N x 4
                        const float* __restrict__ Wl,      // 3 x 64 x 64
                        const float* __restrict__ Wsc,     // 4 x 64 x 64
                        float* __restrict__ out)
{
    __shared__ float ms[4][576];
    __shared__ float fs[4][64];
    const int tid = threadIdx.x;
    const int wid = tid >> 6;
    const int v   = tid & 63;
    const int n   = (blockIdx.x << 2) + wid;
    const int beg = offs[n];
    const int end = offs[n + 1];

    float a0 = 0.f, a1[3] = {0.f, 0.f, 0.f}, a2[5] = {0.f, 0.f, 0.f, 0.f, 0.f};
    for (int k = beg; k < end; ++k) {
        int e = order[k];
        e = __builtin_amdgcn_readfirstlane(e);   // wave-uniform -> scalar loads for y
        const __half* wr = wx + (size_t)e * 192;
        const float x0 = __half2float(wr[v]);
        const float x1 = __half2float(wr[64 + v]);
        const float x2 = __half2float(wr[128 + v]);
        const float* y = ea + e * 9;
        a0 += x0 * y[0];
#pragma unroll
        for (int m = 0; m < 3; ++m) a1[m] += x1 * y[1 + m];
#pragma unroll
        for (int m = 0; m < 5; ++m) a2[m] += x2 * y[4 + m];
    }

    // transpose msg row through this wave's LDS slice (wave-internal, no block barrier)
    float* m = ms[wid];
    m[v] = a0;
#pragma unroll
    for (int mm = 0; mm < 3; ++mm) m[64 + v * 3 + mm] = a1[mm];
#pragma unroll
    for (int mm = 0; mm < 5; ++mm) m[256 + v * 5 + mm] = a2[mm];
    fs[wid][v] = nf[(n << 6) + v];
    // same-wave lockstep: drain LDS writes before cross-lane reads
    asm volatile("s_waitcnt lgkmcnt(0)" ::: "memory");

    float o9[9];
#pragma unroll
    for (int j = 0; j < 9; ++j) o9[j] = 0.f;
    const float* m1 = m + 64;
    const float* m2 = m + 256;

#pragma unroll 8
    for (int u = 0; u < 64; ++u) {
        const float w0 = Wl[(u << 6) + v];
        const float w1 = Wl[4096 + (u << 6) + v];
        const float w2 = Wl[8192 + (u << 6) + v];
        o9[0] += m[u] * w0;
        o9[1] += m1[u * 3 + 0] * w1;
        o9[2] += m1[u * 3 + 1] * w1;
        o9[3] += m1[u * 3 + 2] * w1;
        o9[4] += m2[u * 5 + 0] * w2;
        o9[5] += m2[u * 5 + 1] * w2;
        o9[6] += m2[u * 5 + 2] * w2;
        o9[7] += m2[u * 5 + 3] * w2;
        o9[8] += m2[u * 5 + 4] * w2;
    }
#pragma unroll
    for (int j = 0; j < 9; ++j) out[n * MSG_ROW + v * 9 + j] = o9[j] * 0.125f;

    // sc0[n][v] = (1/16) * sum_a attr[a] * sum_u feat[u] * Wsc[a][u][v]
    const float b0 = na[(n << 2) + 0];
    const float b1 = na[(n << 2) + 1];
    const float b2 = na[(n << 2) + 2];
    const float b3 = na[(n << 2) + 3];
    float sacc = 0.f;
#pragma unroll 8
    for (int u = 0; u < 64; ++u) {
        const float f = fs[wid][u];
        sacc += f * (b0 * Wsc[(u << 6) + v] + b1 * Wsc[4096 + (u << 6) + v] +
                     b2 * Wsc[8192 + (u << 6) + v] + b3 * Wsc[12288 + (u << 6) + v]);
    }
    float* scrow = out + MSG_OFF + n * MSG_ROW;
    scrow[v] = sacc * 0.0625f;
#pragma unroll
    for (int j = 1; j < 9; ++j) scrow[(j << 6) + v] = 0.f;
}

// ============================ fallback (atomic) path ============================

__global__ __launch_bounds__(256, 4)
void edge_kernel_atomic(const float* __restrict__ length,
                        const float* __restrict__ nf,
                        const float* __restrict__ ea,
                        const float* __restrict__ W1,
                        const float* __restrict__ W2,
                        const float* __restrict__ W3,
                        const float* __restrict__ W4,
                        const int*   __restrict__ eidx,
                        float* __restrict__ msg)
{
    __shared__ float buf[4096];
    __shared__ float lenS[512];
    __shared__ float Ys[576];
    __shared__ int   sendS[64];
    __shared__ int   recvS[64];

    const int tid = threadIdx.x;
    const int tx = tid & 15;
    const int ty = tid >> 4;
    const int c0 = tx << 2;
    const int e0 = ty << 2;
    const int ebase = blockIdx.x << 6;

    for (int i = tid; i < 512; i += 256) {
        const int e = i >> 3, k = i & 7;
        lenS[(k << 6) + e] = length[((ebase + e) << 3) + k];
    }
    for (int i = tid; i < 576; i += 256) Ys[i] = ea[ebase * 9 + i];
    if (tid < 64) {
        sendS[tid] = eidx[ebase + tid];
        recvS[tid] = eidx[N_EDGES + ebase + tid];
    }
    __syncthreads();

    {
        float a2[4][4];
#pragma unroll
        for (int i = 0; i < 4; ++i)
#pragma unroll
            for (int j = 0; j < 4; ++j) a2[i][j] = 0.f;
#pragma unroll
        for (int k = 0; k < 8; ++k) {
            const float4 h4 = *(const float4*)&lenS[(k << 6) + e0];
            const float4 w4 = *(const float4*)&W1[(k << 6) + c0];
            const float hv[4] = {h4.x, h4.y, h4.z, h4.w};
            const float wv[4] = {w4.x, w4.y, w4.z, w4.w};
#pragma unroll
            for (int i = 0; i < 4; ++i)
#pragma unroll
                for (int j = 0; j < 4; ++j) a2[i][j] += wv[i] * hv[j];
        }
        layer_store(buf, a2, 0.35355339059327373f, c0, e0);
    }
    __syncthreads();
    {
        float a2[4][4];
        layer_accum(buf, W2, a2, c0, e0);
        __syncthreads();
        layer_store(buf, a2, 0.125f, c0, e0);
    }
    __syncthreads();
    {
        float a2[4][4];
        layer_accum(buf, W3, a2, c0, e0);
        __syncthreads();
        layer_store(buf, a2, 0.125f, c0, e0);
    }
    __syncthreads();

    float wacc[3][4][4];
#pragma unroll
    for (int l = 0; l < 3; ++l)
#pragma unroll
        for (int i = 0; i < 4; ++i)
#pragma unroll
            for (int j = 0; j < 4; ++j) wacc[l][i][j] = 0.f;
#pragma unroll 4
    for (int u = 0; u < 64; ++u) {
        const float4 h4 = *(const float4*)&buf[(u << 6) + e0];
        const float hv[4] = {h4.x, h4.y, h4.z, h4.w};
#pragma unroll
        for (int l = 0; l < 3; ++l) {
            const float4 w4 = *(const float4*)&W4[u * 192 + (l << 6) + c0];
            const float wv[4] = {w4.x, w4.y, w4.z, w4.w};
#pragma unroll
            for (int i = 0; i < 4; ++i)
#pragma unroll
                for (int j = 0; j < 4; ++j) wacc[l][i][j] += wv[i] * hv[j];
        }
    }

#pragma unroll
    for (int j = 0; j < 4; ++j) {
        const int e = e0 + j;
        const int snd = sendS[e];
        const int rcv = recvS[e];
        const float4 nf4 = *(const float4*)&nf[(snd << 6) + c0];
        const float nfv[4] = {nf4.x, nf4.y, nf4.z, nf4.w};
        float* mrow = msg + rcv * MSG_ROW;
        const float y0 = Ys[e * 9 + 0];
        float y1[3], y2[5];
#pragma unroll
        for (int m = 0; m < 3; ++m) y1[m] = Ys[e * 9 + 1 + m];
#pragma unroll
        for (int m = 0; m < 5; ++m) y2[m] = Ys[e * 9 + 4 + m];
#pragma unroll
        for (int i = 0; i < 4; ++i) {
            const int c = c0 + i;
            const float wx0 = wacc[0][i][j] * 0.125f * nfv[i];
            const float wx1 = wacc[1][i][j] * 0.125f * nfv[i];
            const float wx2 = wacc[2][i][j] * 0.125f * nfv[i];
            atomicAdd(&mrow[c], wx0 * y0);
#pragma unroll
            for (int m = 0; m < 3; ++m) atomicAdd(&mrow[64 + c * 3 + m], wx1 * y1[m]);
#pragma unroll
            for (int m = 0; m < 5; ++m) atomicAdd(&mrow[256 + c * 5 + m], wx2 * y2[m]);
        }
    }
}

__global__ __launch_bounds__(256, 4)
void node_kernel(const float* __restrict__ nf,
                 const float* __restrict__ na,
                 const float* __restrict__ Wl,
                 const float* __restrict__ Wsc,
                 float* __restrict__ out)
{
    __shared__ float ms[4][576];
    __shared__ float fs[4][64];
    const int tid = threadIdx.x;
    const int wid = tid >> 6;
    const int v   = tid & 63;
    const int n   = (blockIdx.x << 2) + wid;
    const float* msg = out + MSG_OFF;

#pragma unroll
    for (int j = 0; j < 9; ++j)
        ms[wid][(j << 6) + v] = msg[n * MSG_ROW + (j << 6) + v];
    fs[wid][v] = nf[(n << 6) + v];
    __syncthreads();

    float o9[9];
#pragma unroll
    for (int j = 0; j < 9; ++j) o9[j] = 0.f;
    const float* m0 = &ms[wid][0];
    const float* m1 = &ms[wid][64];
    const float* m2 = &ms[wid][256];

#pragma unroll 8
    for (int u = 0; u < 64; ++u) {
        const float w0 = Wl[(u << 6) + v];
        const float w1 = Wl[4096 + (u << 6) + v];
        const float w2 = Wl[8192 + (u << 6) + v];
        o9[0] += m0[u] * w0;
        o9[1] += m1[u * 3 + 0] * w1;
        o9[2] += m1[u * 3 + 1] * w1;
        o9[3] += m1[u * 3 + 2] * w1;
        o9[4] += m2[u * 5 + 0] * w2;
        o9[5] += m2[u * 5 + 1] * w2;
        o9[6] += m2[u * 5 + 2] * w2;
        o9[7] += m2[u * 5 + 3] * w2;
        o9[8] += m2[u * 5 + 4] * w2;
    }
#pragma unroll
    for (int j = 0; j < 9; ++j) out[n * MSG_ROW + v * 9 + j] = o9[j] * 0.125f;

    const float b0 = na[(n << 2) + 0];
    const float b1 = na[(n << 2) + 1];
    const float b2 = na[(n << 2) + 2];
    const float b3 = na[(n << 2) + 3];
    float sacc = 0.f;
#pragma unroll 8
    for (int u = 0; u < 64; ++u) {
        const float f = fs[wid][u];
        sacc += f * (b0 * Wsc[(u << 6) + v] + b1 * Wsc[4096 + (u << 6) + v] +
                     b2 * Wsc[8192 + (u << 6) + v] + b3 * Wsc[12288 + (u << 6) + v]);
    }
    float* scrow = out + MSG_OFF + n * MSG_ROW;
    scrow[v] = sacc * 0.0625f;
#pragma unroll
    for (int j = 1; j < 9; ++j) scrow[(j << 6) + v] = 0.f;
}

extern "C" void kernel_launch(void* const* d_in, const int* in_sizes, int n_in,
                              void* d_out, int out_size, void* d_ws, size_t ws_size,
                              hipStream_t stream) {
    const float* length = (const float*)d_in[0];
    const float* nfeat  = (const float*)d_in[1];
    const float* nattr  = (const float*)d_in[2];
    const float* eattr  = (const float*)d_in[3];
    const float* W1     = (const float*)d_in[4];
    const float* W2     = (const float*)d_in[5];
    const float* W3     = (const float*)d_in[6];
    const float* W4     = (const float*)d_in[7];
    const float* Wl     = (const float*)d_in[8];
    const float* Wsc    = (const float*)d_in[9];
    const int*   eidx   = (const int*)d_in[10];
    float* out = (float*)d_out;

    // ws layout: wx[E*192 fp16] | counts[N] | offsets[N+1] | cursor[N] | order[E] | bsum[128] | bbase[128]
    __half* wx     = (__half*)d_ws;
    int*   counts  = (int*)((char*)d_ws + (size_t)N_EDGES * 192 * 2);
    int*   offsets = counts + N_NODES;
    int*   cursor  = offsets + N_NODES + 1;
    int*   order   = cursor + N_NODES;
    int*   bsum    = order + N_EDGES;
    int*   bbase   = bsum + 128;
    const size_t need = (size_t)N_EDGES * 192 * 2 +
                        (size_t)(N_NODES * 3 + 1 + N_EDGES + 256) * 4;

    if (ws_size >= need) {
        hipMemsetAsync(counts, 0, N_NODES * sizeof(int), stream);
        hist_kernel<<<N_EDGES / 256, 256, 0, stream>>>(eidx, counts);
        scan1_kernel<<<NBLK_SCAN, SCAN_BS, 0, stream>>>(counts, offsets, bsum);
        scan2_kernel<<<1, 128, 0, stream>>>(bsum, bbase, offsets);
        scan3_kernel<<<NBLK_SCAN, SCAN_BS, 0, stream>>>(offsets, bbase, cursor);
        scatter_kernel<<<N_EDGES / 256, 256, 0, stream>>>(eidx, cursor, order);
        edge_mlp_kernel<<<N_EDGES / 64, 256, 0, stream>>>(length, nfeat, W1, W2, W3, W4,
                                                          eidx, wx);
        gather_node_kernel<<<N_NODES / 4, 256, 0, stream>>>(wx, eattr, offsets, order,
                                                            nfeat, nattr, Wl, Wsc, out);
    } else {
        // fallback: atomic scatter path
        hipMemsetAsync(out + MSG_OFF, 0, (size_t)N_NODES * MSG_ROW * sizeof(float), stream);
        edge_kernel_atomic<<<N_EDGES / 64, 256, 0, stream>>>(length, nfeat, eattr,
                                                             W1, W2, W3, W4, eidx,
                                                             out + MSG_OFF);
        node_kernel<<<N_NODES / 4, 256, 0, stream>>>(nfeat, nattr, Wl, Wsc, out);
    }
}

// Round 5
// 227.414 us; speedup vs baseline: 4.0280x; 1.7277x over previous
//
#include <hip/hip_runtime.h>
#include <hip/hip_fp16.h>

#define N_NODES 20000
#define N_EDGES 320000
#define MSG_ROW 576
#define MSG_OFF 11520000   // N_NODES * 576 : sc region of d_out (fallback msg buffer)
#define SCAN_BS 256
#define NBLK_SCAN ((N_NODES + SCAN_BS - 1) / SCAN_BS)   // 79

typedef _Float16 f16;
typedef _Float16 f16x4 __attribute__((ext_vector_type(4)));
typedef _Float16 f16x8 __attribute__((ext_vector_type(8)));
typedef float f32x4 __attribute__((ext_vector_type(4)));

// LDS layout (bytes) for edge_mlp_mfma
#define OFF_WT4 0        // 192x64 f16 = 24576
#define OFF_W1T 24576    // 64x32 f16  = 4096  (k>=8 zero-padded)
#define OFF_WT2 28672    // 64x64 f16  = 8192
#define OFF_WT3 36864    // 8192
#define OFF_H0  45056    // 64x32 f16  = 4096
#define OFF_HT  49152    // 64x64 f16  = 8192
#define LDS_TOTAL 57344
// wxT (64x192 f16 = 24576 B) aliases W1T/WT2/WT3/H0 — all dead after L4 mfma
#define OFF_WXT 24576

#define WIMG_HALF 22528          // total f16 elems in weight image
#define WIMG_BYTES 45056

__device__ __forceinline__ float silu_f(float x) {
    return x * (1.0f / (1.0f + __expf(-x)));
}

// ============================ weight image pre-kernel ============================
// Builds transposed + XOR-swizzled f16 images: [Wt4 | W1t | Wt2 | Wt3].
// Swizzle: within a row, 16B granule g stored at g ^ (row & mask).

__global__ __launch_bounds__(256)
void wimg_kernel(const float* __restrict__ W1, const float* __restrict__ W2,
                 const float* __restrict__ W3, const float* __restrict__ W4,
                 f16* __restrict__ img) {
    const int p = blockIdx.x * 256 + threadIdx.x;
    if (p >= WIMG_HALF) return;
    float v;
    if (p < 12288) {                         // Wt4 [192][64]
        const int m = p >> 6, rem = p & 63, g = rem >> 3, j = rem & 7;
        const int k = ((g ^ (m & 7)) << 3) | j;
        v = W4[k * 192 + m];
    } else if (p < 14336) {                  // W1t [64][32], k>=8 -> 0
        const int q = p - 12288;
        const int m = q >> 5, rem = q & 31, g = rem >> 3, j = rem & 7;
        const int k = ((g ^ (m & 3)) << 3) | j;
        v = (k < 8) ? W1[k * 64 + m] : 0.f;
    } else if (p < 18432) {                  // Wt2 [64][64]
        const int q = p - 14336;
        const int m = q >> 6, rem = q & 63, g = rem >> 3, j = rem & 7;
        const int k = ((g ^ (m & 7)) << 3) | j;
        v = W2[k * 64 + m];
    } else {                                 // Wt3 [64][64]
        const int q = p - 18432;
        const int m = q >> 6, rem = q & 63, g = rem >> 3, j = rem & 7;
        const int k = ((g ^ (m & 7)) << 3) | j;
        v = W3[k * 64 + m];
    }
    img[p] = (f16)v;
}

// ============================ CSR build ============================

__global__ __launch_bounds__(256)
void hist_kernel(const int* __restrict__ eidx, int* __restrict__ counts) {
    const int e = blockIdx.x * 256 + threadIdx.x;
    if (e < N_EDGES) atomicAdd(&counts[eidx[N_EDGES + e]], 1);
}

__global__ __launch_bounds__(SCAN_BS)
void scan1_kernel(const int* __restrict__ counts, int* __restrict__ offs,
                  int* __restrict__ bsum) {
    __shared__ int sm[SCAN_BS];
    const int tid = threadIdx.x;
    const int i = blockIdx.x * SCAN_BS + tid;
    const int v = (i < N_NODES) ? counts[i] : 0;
    sm[tid] = v;
    __syncthreads();
#pragma unroll
    for (int off = 1; off < SCAN_BS; off <<= 1) {
        const int t = (tid >= off) ? sm[tid - off] : 0;
        __syncthreads();
        sm[tid] += t;
        __syncthreads();
    }
    if (i < N_NODES) offs[i] = sm[tid] - v;
    if (tid == SCAN_BS - 1) bsum[blockIdx.x] = sm[tid];
}

__global__ __launch_bounds__(128)
void scan2_kernel(const int* __restrict__ bsum, int* __restrict__ bbase,
                  int* __restrict__ offs) {
    __shared__ int sm[128];
    const int tid = threadIdx.x;
    const int v = (tid < NBLK_SCAN) ? bsum[tid] : 0;
    sm[tid] = v;
    __syncthreads();
#pragma unroll
    for (int off = 1; off < 128; off <<= 1) {
        const int t = (tid >= off) ? sm[tid - off] : 0;
        __syncthreads();
        sm[tid] += t;
        __syncthreads();
    }
    if (tid < NBLK_SCAN) bbase[tid] = sm[tid] - v;
    if (tid == 127) offs[N_NODES] = sm[127];
}

__global__ __launch_bounds__(SCAN_BS)
void scan3_kernel(int* __restrict__ offs, const int* __restrict__ bbase,
                  int* __restrict__ cursor) {
    const int i = blockIdx.x * SCAN_BS + threadIdx.x;
    if (i < N_NODES) {
        const int o = offs[i] + bbase[blockIdx.x];
        offs[i] = o;
        cursor[i] = o;
    }
}

__global__ __launch_bounds__(256)
void scatter_kernel(const int* __restrict__ eidx, int* __restrict__ cursor,
                    int* __restrict__ order) {
    const int e = blockIdx.x * 256 + threadIdx.x;
    if (e < N_EDGES) {
        const int pos = atomicAdd(&cursor[eidx[N_EDGES + e]], 1);
        order[pos] = e;
    }
}

// ============================ MFMA edge MLP ============================
// 64 edges/block, 4 waves. C[out][edge] tiles via mfma_f32_16x16x32_f16:
// A-frag = Wt[out-row][k0..k0+7] (b128), B-frag = hT[edge-row][k0..k0+7] (b128),
// C/D: col=lane&15 (edge), row=(lane>>4)*4+reg (out). All LDS rows XOR-swizzled
// on 16B granules (g ^= row & mask) -> conflict-free reads and b64 C-stores.

__global__ __launch_bounds__(256)
void edge_mlp_mfma(const float* __restrict__ length,   // E x 8
                   const float* __restrict__ nf,       // N x 64
                   const int*   __restrict__ eidx,     // 2 x E
                   const f16*   __restrict__ wimg,     // weight image
                   f16* __restrict__ wx)               // E x 192 f16
{
    __shared__ __align__(16) char s[LDS_TOTAL];
    __shared__ int sendS[64];

    const int tid = threadIdx.x;
    const int ebase = blockIdx.x << 6;

    // ---- stage weight image (linear copy, 45056 B) ----
    {
        const uint4* src = (const uint4*)wimg;
        uint4* dst = (uint4*)s;
#pragma unroll
        for (int i = 0; i < 11; ++i) dst[i * 256 + tid] = src[i * 256 + tid];
    }
    // ---- stage h0T (64 x 32 f16, k>=8 zeroed), swizzle mask 3 ----
    if (tid < 64) {
        const int e = tid;
        const float4 q0 = *(const float4*)&length[(size_t)(ebase + e) * 8];
        const float4 q1 = *(const float4*)&length[(size_t)(ebase + e) * 8 + 4];
        f16x8 h;
        h[0] = (f16)q0.x; h[1] = (f16)q0.y; h[2] = (f16)q0.z; h[3] = (f16)q0.w;
        h[4] = (f16)q1.x; h[5] = (f16)q1.y; h[6] = (f16)q1.z; h[7] = (f16)q1.w;
        *(f16x8*)(s + OFF_H0 + e * 64 + ((0 ^ (e & 3)) << 4)) = h;
        sendS[e] = eidx[ebase + e];
    } else {
        const int idx = tid - 64;            // 192 threads = 64 edges x 3 granules
        const int e = idx / 3, gz = 1 + idx - (idx / 3) * 3;
        uint4 z; z.x = 0; z.y = 0; z.z = 0; z.w = 0;
        *(uint4*)(s + OFF_H0 + e * 64 + ((gz ^ (e & 3)) << 4)) = z;
    }
    __syncthreads();

    const int lane = tid & 63, w = tid >> 6;
    const int lm = lane & 15, lg = lane >> 4;
    const int mrow = w * 16 + lm;            // A-operand row (out-ch) for L1-L3
    const int r0 = lg << 2;                  // C row offset within 16x16 tile

    const f32x4 zacc = {0.f, 0.f, 0.f, 0.f};
    f32x4 acc[4];

    // ---- L1: 8(->32 padded) -> 64 ----
    {
        const f16x8 a = *(const f16x8*)(s + OFF_W1T + mrow * 64 + ((lg ^ (mrow & 3)) << 4));
#pragma unroll
        for (int nt = 0; nt < 4; ++nt) {
            const int e = nt * 16 + lm;
            const f16x8 b = *(const f16x8*)(s + OFF_H0 + e * 64 + ((lg ^ (e & 3)) << 4));
            acc[nt] = __builtin_amdgcn_mfma_f32_16x16x32_f16(a, b, zacc, 0, 0, 0);
        }
    }
    // write h1 -> hT (L1 inputs are h0T/W1t: no in-place hazard)
    {
        const int c = w * 16 + r0;
#pragma unroll
        for (int nt = 0; nt < 4; ++nt) {
            const int e = nt * 16 + lm;
            f16x4 pk;
            pk[0] = (f16)silu_f(acc[nt][0] * 0.35355339059f);
            pk[1] = (f16)silu_f(acc[nt][1] * 0.35355339059f);
            pk[2] = (f16)silu_f(acc[nt][2] * 0.35355339059f);
            pk[3] = (f16)silu_f(acc[nt][3] * 0.35355339059f);
            *(f16x4*)(s + OFF_HT + e * 128 + (((c >> 3) ^ (e & 7)) << 4) + ((c & 7) << 1)) = pk;
        }
    }
    __syncthreads();

    // ---- L2: 64 -> 64 (in-place hT: mfma-all -> barrier -> store -> barrier) ----
#pragma unroll
    for (int nt = 0; nt < 4; ++nt) acc[nt] = zacc;
#pragma unroll
    for (int kh = 0; kh < 2; ++kh) {
        const int g = (kh << 2) + lg;
        const f16x8 a = *(const f16x8*)(s + OFF_WT2 + mrow * 128 + ((g ^ (mrow & 7)) << 4));
#pragma unroll
        for (int nt = 0; nt < 4; ++nt) {
            const int e = nt * 16 + lm;
            const f16x8 b = *(const f16x8*)(s + OFF_HT + e * 128 + ((g ^ (e & 7)) << 4));
            acc[nt] = __builtin_amdgcn_mfma_f32_16x16x32_f16(a, b, acc[nt], 0, 0, 0);
        }
    }
    __syncthreads();
    {
        const int c = w * 16 + r0;
#pragma unroll
        for (int nt = 0; nt < 4; ++nt) {
            const int e = nt * 16 + lm;
            f16x4 pk;
            pk[0] = (f16)silu_f(acc[nt][0] * 0.125f);
            pk[1] = (f16)silu_f(acc[nt][1] * 0.125f);
            pk[2] = (f16)silu_f(acc[nt][2] * 0.125f);
            pk[3] = (f16)silu_f(acc[nt][3] * 0.125f);
            *(f16x4*)(s + OFF_HT + e * 128 + (((c >> 3) ^ (e & 7)) << 4) + ((c & 7) << 1)) = pk;
        }
    }
    __syncthreads();

    // ---- L3: 64 -> 64 ----
#pragma unroll
    for (int nt = 0; nt < 4; ++nt) acc[nt] = zacc;
#pragma unroll
    for (int kh = 0; kh < 2; ++kh) {
        const int g = (kh << 2) + lg;
        const f16x8 a = *(const f16x8*)(s + OFF_WT3 + mrow * 128 + ((g ^ (mrow & 7)) << 4));
#pragma unroll
        for (int nt = 0; nt < 4; ++nt) {
            const int e = nt * 16 + lm;
            const f16x8 b = *(const f16x8*)(s + OFF_HT + e * 128 + ((g ^ (e & 7)) << 4));
            acc[nt] = __builtin_amdgcn_mfma_f32_16x16x32_f16(a, b, acc[nt], 0, 0, 0);
        }
    }
    __syncthreads();
    {
        const int c = w * 16 + r0;
#pragma unroll
        for (int nt = 0; nt < 4; ++nt) {
            const int e = nt * 16 + lm;
            f16x4 pk;
            pk[0] = (f16)silu_f(acc[nt][0] * 0.125f);
            pk[1] = (f16)silu_f(acc[nt][1] * 0.125f);
            pk[2] = (f16)silu_f(acc[nt][2] * 0.125f);
            pk[3] = (f16)silu_f(acc[nt][3] * 0.125f);
            *(f16x4*)(s + OFF_HT + e * 128 + (((c >> 3) ^ (e & 7)) << 4) + ((c & 7) << 1)) = pk;
        }
    }
    __syncthreads();

    // ---- L4: 64 -> 192 (no silu), x 0.125 x nf[sender][c] ----
    f32x4 acc4[3][4];
#pragma unroll
    for (int p = 0; p < 3; ++p)
#pragma unroll
        for (int nt = 0; nt < 4; ++nt) acc4[p][nt] = zacc;
#pragma unroll
    for (int kh = 0; kh < 2; ++kh) {
        const int g = (kh << 2) + lg;
        f16x8 ap[3];
#pragma unroll
        for (int p = 0; p < 3; ++p) {
            const int m4 = p * 64 + mrow;
            ap[p] = *(const f16x8*)(s + OFF_WT4 + m4 * 128 + ((g ^ (m4 & 7)) << 4));
        }
#pragma unroll
        for (int nt = 0; nt < 4; ++nt) {
            const int e = nt * 16 + lm;
            const f16x8 b = *(const f16x8*)(s + OFF_HT + e * 128 + ((g ^ (e & 7)) << 4));
#pragma unroll
            for (int p = 0; p < 3; ++p)
                acc4[p][nt] = __builtin_amdgcn_mfma_f32_16x16x32_f16(ap[p], b, acc4[p][nt], 0, 0, 0);
        }
    }
    __syncthreads();   // Wt4/hT reads done -> wxT aliasing of W1t/Wt2/Wt3/h0T is safe

    // store wxT[edge][192] (swizzled), lane's 4 consecutive out-channels = b64
#pragma unroll
    for (int nt = 0; nt < 4; ++nt) {
        const int e = nt * 16 + lm;
        const int snd = sendS[e];
        const float4 nf4 = *(const float4*)&nf[(size_t)snd * 64 + w * 16 + r0];
#pragma unroll
        for (int p = 0; p < 3; ++p) {
            const int c = p * 64 + w * 16 + r0;
            f16x4 pk;
            pk[0] = (f16)(acc4[p][nt][0] * 0.125f * nf4.x);
            pk[1] = (f16)(acc4[p][nt][1] * 0.125f * nf4.y);
            pk[2] = (f16)(acc4[p][nt][2] * 0.125f * nf4.z);
            pk[3] = (f16)(acc4[p][nt][3] * 0.125f * nf4.w);
            *(f16x4*)(s + OFF_WXT + e * 384 + (((c >> 3) ^ (e & 7)) << 4) + ((c & 7) << 1)) = pk;
        }
    }
    __syncthreads();

    // coalesced copy-out: 64 x 384 B, unswizzling granules
#pragma unroll
    for (int it = 0; it < 6; ++it) {
        const int chunk = it * 256 + tid;               // 1536 chunks
        const int e = chunk / 24, g = chunk - e * 24;
        const uint4 v = *(const uint4*)(s + OFF_WXT + e * 384 + ((g ^ (e & 7)) << 4));
        *(uint4*)((char*)wx + (size_t)(ebase + e) * 384 + g * 16) = v;
    }
}

// ============================ fused gather + node transform ============================

__global__ __launch_bounds__(256, 8)
void gather_node_kernel(const __half* __restrict__ wx,     // E x 192 f16
                        const float* __restrict__ ea,      // E x 9
                        const int* __restrict__ offs,      // N+1
                        const int* __restrict__ order,     // E
                        const float* __restrict__ nf,      // N x 64
                        const float* __restrict__ na,      // N x 4
                        const float* __restrict__ Wl,      // 3 x 64 x 64
                        const float* __restrict__ Wsc,     // 4 x 64 x 64
                        float* __restrict__ out)
{
    __shared__ float ms[4][576];
    __shared__ float fs[4][64];
    const int tid = threadIdx.x;
    const int wid = tid >> 6;
    const int v   = tid & 63;
    const int n   = (blockIdx.x << 2) + wid;
    const int beg = offs[n];
    const int end = offs[n + 1];

    float a0 = 0.f, a1[3] = {0.f, 0.f, 0.f}, a2[5] = {0.f, 0.f, 0.f, 0.f, 0.f};
    for (int k = beg; k < end; ++k) {
        int e = order[k];
        e = __builtin_amdgcn_readfirstlane(e);   // wave-uniform -> scalar loads for y
        const __half* wr = wx + (size_t)e * 192;
        const float x0 = __half2float(wr[v]);
        const float x1 = __half2float(wr[64 + v]);
        const float x2 = __half2float(wr[128 + v]);
        const float* y = ea + e * 9;
        a0 += x0 * y[0];
#pragma unroll
        for (int m = 0; m < 3; ++m) a1[m] += x1 * y[1 + m];
#pragma unroll
        for (int m = 0; m < 5; ++m) a2[m] += x2 * y[4 + m];
    }

    float* m = ms[wid];
    m[v] = a0;
#pragma unroll
    for (int mm = 0; mm < 3; ++mm) m[64 + v * 3 + mm] = a1[mm];
#pragma unroll
    for (int mm = 0; mm < 5; ++mm) m[256 + v * 5 + mm] = a2[mm];
    fs[wid][v] = nf[(n << 6) + v];
    asm volatile("s_waitcnt lgkmcnt(0)" ::: "memory");

    float o9[9];
#pragma unroll
    for (int j = 0; j < 9; ++j) o9[j] = 0.f;
    const float* m1 = m + 64;
    const float* m2 = m + 256;

#pragma unroll 8
    for (int u = 0; u < 64; ++u) {
        const float w0 = Wl[(u << 6) + v];
        const float w1 = Wl[4096 + (u << 6) + v];
        const float w2 = Wl[8192 + (u << 6) + v];
        o9[0] += m[u] * w0;
        o9[1] += m1[u * 3 + 0] * w1;
        o9[2] += m1[u * 3 + 1] * w1;
        o9[3] += m1[u * 3 + 2] * w1;
        o9[4] += m2[u * 5 + 0] * w2;
        o9[5] += m2[u * 5 + 1] * w2;
        o9[6] += m2[u * 5 + 2] * w2;
        o9[7] += m2[u * 5 + 3] * w2;
        o9[8] += m2[u * 5 + 4] * w2;
    }
#pragma unroll
    for (int j = 0; j < 9; ++j) out[n * MSG_ROW + v * 9 + j] = o9[j] * 0.125f;

    const float b0 = na[(n << 2) + 0];
    const float b1 = na[(n << 2) + 1];
    const float b2 = na[(n << 2) + 2];
    const float b3 = na[(n << 2) + 3];
    float sacc = 0.f;
#pragma unroll 8
    for (int u = 0; u < 64; ++u) {
        const float f = fs[wid][u];
        sacc += f * (b0 * Wsc[(u << 6) + v] + b1 * Wsc[4096 + (u << 6) + v] +
                     b2 * Wsc[8192 + (u << 6) + v] + b3 * Wsc[12288 + (u << 6) + v]);
    }
    float* scrow = out + MSG_OFF + n * MSG_ROW;
    scrow[v] = sacc * 0.0625f;
#pragma unroll
    for (int j = 1; j < 9; ++j) scrow[(j << 6) + v] = 0.f;
}

// ============================ fallback (atomic, fp32) path ============================

__device__ __forceinline__ void layer_accum(const float* src, const float* __restrict__ W,
                                            float a2[4][4], int c0, int e0) {
#pragma unroll
    for (int i = 0; i < 4; ++i)
#pragma unroll
        for (int j = 0; j < 4; ++j) a2[i][j] = 0.f;
#pragma unroll 8
    for (int u = 0; u < 64; ++u) {
        const float4 h4 = *(const float4*)&src[(u << 6) + e0];
        const float4 w4 = *(const float4*)&W[(u << 6) + c0];
        const float hv[4] = {h4.x, h4.y, h4.z, h4.w};
        const float wv[4] = {w4.x, w4.y, w4.z, w4.w};
#pragma unroll
        for (int i = 0; i < 4; ++i)
#pragma unroll
            for (int j = 0; j < 4; ++j) a2[i][j] += wv[i] * hv[j];
    }
}

__device__ __forceinline__ void layer_store(float* dst, const float a2[4][4],
                                            float scale, int c0, int e0) {
#pragma unroll
    for (int i = 0; i < 4; ++i) {
        float4 v;
        v.x = silu_f(a2[i][0] * scale);
        v.y = silu_f(a2[i][1] * scale);
        v.z = silu_f(a2[i][2] * scale);
        v.w = silu_f(a2[i][3] * scale);
        *(float4*)&dst[((c0 + i) << 6) + e0] = v;
    }
}

__global__ __launch_bounds__(256, 4)
void edge_kernel_atomic(const float* __restrict__ length,
                        const float* __restrict__ nf,
                        const float* __restrict__ ea,
                        const float* __restrict__ W1,
                        const float* __restrict__ W2,
                        const float* __restrict__ W3,
                        const float* __restrict__ W4,
                        const int*   __restrict__ eidx,
                        float* __restrict__ msg)
{
    __shared__ float buf[4096];
    __shared__ float lenS[512];
    __shared__ float Ys[576];
    __shared__ int   sendS[64];
    __shared__ int   recvS[64];

    const int tid = threadIdx.x;
    const int tx = tid & 15;
    const int ty = tid >> 4;
    const int c0 = tx << 2;
    const int e0 = ty << 2;
    const int ebase = blockIdx.x << 6;

    for (int i = tid; i < 512; i += 256) {
        const int e = i >> 3, k = i & 7;
        lenS[(k << 6) + e] = length[((ebase + e) << 3) + k];
    }
    for (int i = tid; i < 576; i += 256) Ys[i] = ea[ebase * 9 + i];
    if (tid < 64) {
        sendS[tid] = eidx[ebase + tid];
        recvS[tid] = eidx[N_EDGES + ebase + tid];
    }
    __syncthreads();

    {
        float a2[4][4];
#pragma unroll
        for (int i = 0; i < 4; ++i)
#pragma unroll
            for (int j = 0; j < 4; ++j) a2[i][j] = 0.f;
#pragma unroll
        for (int k = 0; k < 8; ++k) {
            const float4 h4 = *(const float4*)&lenS[(k << 6) + e0];
            const float4 w4 = *(const float4*)&W1[(k << 6) + c0];
            const float hv[4] = {h4.x, h4.y, h4.z, h4.w};
            const float wv[4] = {w4.x, w4.y, w4.z, w4.w};
#pragma unroll
            for (int i = 0; i < 4; ++i)
#pragma unroll
                for (int j = 0; j < 4; ++j) a2[i][j] += wv[i] * hv[j];
        }
        layer_store(buf, a2, 0.35355339059327373f, c0, e0);
    }
    __syncthreads();
    {
        float a2[4][4];
        layer_accum(buf, W2, a2, c0, e0);
        __syncthreads();
        layer_store(buf, a2, 0.125f, c0, e0);
    }
    __syncthreads();
    {
        float a2[4][4];
        layer_accum(buf, W3, a2, c0, e0);
        __syncthreads();
        layer_store(buf, a2, 0.125f, c0, e0);
    }
    __syncthreads();

    float wacc[3][4][4];
#pragma unroll
    for (int l = 0; l < 3; ++l)
#pragma unroll
        for (int i = 0; i < 4; ++i)
#pragma unroll
            for (int j = 0; j < 4; ++j) wacc[l][i][j] = 0.f;
#pragma unroll 4
    for (int u = 0; u < 64; ++u) {
        const float4 h4 = *(const float4*)&buf[(u << 6) + e0];
        const float hv[4] = {h4.x, h4.y, h4.z, h4.w};
#pragma unroll
        for (int l = 0; l < 3; ++l) {
            const float4 w4 = *(const float4*)&W4[u * 192 + (l << 6) + c0];
            const float wv[4] = {w4.x, w4.y, w4.z, w4.w};
#pragma unroll
            for (int i = 0; i < 4; ++i)
#pragma unroll
                for (int j = 0; j < 4; ++j) wacc[l][i][j] += wv[i] * hv[j];
        }
    }

#pragma unroll
    for (int j = 0; j < 4; ++j) {
        const int e = e0 + j;
        const int snd = sendS[e];
        const int rcv = recvS[e];
        const float4 nf4 = *(const float4*)&nf[(snd << 6) + c0];
        const float nfv[4] = {nf4.x, nf4.y, nf4.z, nf4.w};
        float* mrow = msg + rcv * MSG_ROW;
        const float y0 = Ys[e * 9 + 0];
        float y1[3], y2[5];
#pragma unroll
        for (int m = 0; m < 3; ++m) y1[m] = Ys[e * 9 + 1 + m];
#pragma unroll
        for (int m = 0; m < 5; ++m) y2[m] = Ys[e * 9 + 4 + m];
#pragma unroll
        for (int i = 0; i < 4; ++i) {
            const int c = c0 + i;
            const float wx0 = wacc[0][i][j] * 0.125f * nfv[i];
            const float wx1 = wacc[1][i][j] * 0.125f * nfv[i];
            const float wx2 = wacc[2][i][j] * 0.125f * nfv[i];
            atomicAdd(&mrow[c], wx0 * y0);
#pragma unroll
            for (int m = 0; m < 3; ++m) atomicAdd(&mrow[64 + c * 3 + m], wx1 * y1[m]);
#pragma unroll
            for (int m = 0; m < 5; ++m) atomicAdd(&mrow[256 + c * 5 + m], wx2 * y2[m]);
        }
    }
}

__global__ __launch_bounds__(256, 4)
void node_kernel(const float* __restrict__ nf,
                 const float* __restrict__ na,
                 const float* __restrict__ Wl,
                 const float* __restrict__ Wsc,
                 float* __restrict__ out)
{
    __shared__ float ms[4][576];
    __shared__ float fs[4][64];
    const int tid = threadIdx.x;
    const int wid = tid >> 6;
    const int v   = tid & 63;
    const int n   = (blockIdx.x << 2) + wid;
    const float* msg = out + MSG_OFF;

#pragma unroll
    for (int j = 0; j < 9; ++j)
        ms[wid][(j << 6) + v] = msg[n * MSG_ROW + (j << 6) + v];
    fs[wid][v] = nf[(n << 6) + v];
    __syncthreads();

    float o9[9];
#pragma unroll
    for (int j = 0; j < 9; ++j) o9[j] = 0.f;
    const float* m0 = &ms[wid][0];
    const float* m1 = &ms[wid][64];
    const float* m2 = &ms[wid][256];

#pragma unroll 8
    for (int u = 0; u < 64; ++u) {
        const float w0 = Wl[(u << 6) + v];
        const float w1 = Wl[4096 + (u << 6) + v];
        const float w2 = Wl[8192 + (u << 6) + v];
        o9[0] += m0[u] * w0;
        o9[1] += m1[u * 3 + 0] * w1;
        o9[2] += m1[u * 3 + 1] * w1;
        o9[3] += m1[u * 3 + 2] * w1;
        o9[4] += m2[u * 5 + 0] * w2;
        o9[5] += m2[u * 5 + 1] * w2;
        o9[6] += m2[u * 5 + 2] * w2;
        o9[7] += m2[u * 5 + 3] * w2;
        o9[8] += m2[u * 5 + 4] * w2;
    }
#pragma unroll
    for (int j = 0; j < 9; ++j) out[n * MSG_ROW + v * 9 + j] = o9[j] * 0.125f;

    const float b0 = na[(n << 2) + 0];
    const float b1 = na[(n << 2) + 1];
    const float b2 = na[(n << 2) + 2];
    const float b3 = na[(n << 2) + 3];
    float sacc = 0.f;
#pragma unroll 8
    for (int u = 0; u < 64; ++u) {
        const float f = fs[wid][u];
        sacc += f * (b0 * Wsc[(u << 6) + v] + b1 * Wsc[4096 + (u << 6) + v] +
                     b2 * Wsc[8192 + (u << 6) + v] + b3 * Wsc[12288 + (u << 6) + v]);
    }
    float* scrow = out + MSG_OFF + n * MSG_ROW;
    scrow[v] = sacc * 0.0625f;
#pragma unroll
    for (int j = 1; j < 9; ++j) scrow[(j << 6) + v] = 0.f;
}

extern "C" void kernel_launch(void* const* d_in, const int* in_sizes, int n_in,
                              void* d_out, int out_size, void* d_ws, size_t ws_size,
                              hipStream_t stream) {
    const float* length = (const float*)d_in[0];
    const float* nfeat  = (const float*)d_in[1];
    const float* nattr  = (const float*)d_in[2];
    const float* eattr  = (const float*)d_in[3];
    const float* W1     = (const float*)d_in[4];
    const float* W2     = (const float*)d_in[5];
    const float* W3     = (const float*)d_in[6];
    const float* W4     = (const float*)d_in[7];
    const float* Wl     = (const float*)d_in[8];
    const float* Wsc    = (const float*)d_in[9];
    const int*   eidx   = (const int*)d_in[10];
    float* out = (float*)d_out;

    // ws layout: Wimg (45056 B) | wx[E*192 f16] | counts[N] | offs[N+1] | cursor[N] | order[E] | bsum[128] | bbase[128]
    f16*    wimg   = (f16*)d_ws;
    __half* wx     = (__half*)((char*)d_ws + WIMG_BYTES);
    int*   counts  = (int*)((char*)d_ws + WIMG_BYTES + (size_t)N_EDGES * 192 * 2);
    int*   offsets = counts + N_NODES;
    int*   cursor  = offsets + N_NODES + 1;
    int*   order   = cursor + N_NODES;
    int*   bsum    = order + N_EDGES;
    int*   bbase   = bsum + 128;
    const size_t need = WIMG_BYTES + (size_t)N_EDGES * 192 * 2 +
                        (size_t)(N_NODES * 3 + 1 + N_EDGES + 256) * 4;

    if (ws_size >= need) {
        hipMemsetAsync(counts, 0, N_NODES * sizeof(int), stream);
        wimg_kernel<<<(WIMG_HALF + 255) / 256, 256, 0, stream>>>(W1, W2, W3, W4, wimg);
        hist_kernel<<<N_EDGES / 256, 256, 0, stream>>>(eidx, counts);
        scan1_kernel<<<NBLK_SCAN, SCAN_BS, 0, stream>>>(counts, offsets, bsum);
        scan2_kernel<<<1, 128, 0, stream>>>(bsum, bbase, offsets);
        scan3_kernel<<<NBLK_SCAN, SCAN_BS, 0, stream>>>(offsets, bbase, cursor);
        scatter_kernel<<<N_EDGES / 256, 256, 0, stream>>>(eidx, cursor, order);
        edge_mlp_mfma<<<N_EDGES / 64, 256, 0, stream>>>(length, nfeat, eidx, wimg, (f16*)wx);
        gather_node_kernel<<<N_NODES / 4, 256, 0, stream>>>(wx, eattr, offsets, order,
                                                            nfeat, nattr, Wl, Wsc, out);
    } else {
        hipMemsetAsync(out + MSG_OFF, 0, (size_t)N_NODES * MSG_ROW * sizeof(float), stream);
        edge_kernel_atomic<<<N_EDGES / 64, 256, 0, stream>>>(length, nfeat, eattr,
                                                             W1, W2, W3, W4, eidx,
                                                             out + MSG_OFF);
        node_kernel<<<N_NODES / 4, 256, 0, stream>>>(nfeat, nattr, Wl, Wsc, out);
    }
}